// Round 1
// baseline (85.558 us; speedup 1.0000x reference)
//
#include <hip/hip_runtime.h>

// TopologyAwareAttention — R10 restructure.
// Model: dur = ~58us fixed (256MiB ws poison fill ~40us @83% HBM + launch) +
//        7us/node * 2 nodes + kernel work. Only the work term is ours.
// R10: move stats (hist -> mean -> 451-LUT) OUT of k1 into every k2 block,
// computed redundantly (~2.5us VALU, parallel across 198 blocks, overlapped
// with k2's own attn streaming). k1 becomes pure argmax: no in-kernel
// polling, no tags (kernel boundary is the sync — same guarantee the old
// plain lutp store relied on). All float chains copied verbatim from R9 so
// absmax stays bit-identical.
//  f(t) = sum_e relu(t*w1[e]+b1[e]) * mean_h(w2[e,h]) + mean(b2)
//  centers on 16x16 grid => d2 = dx^2+dy^2 in [0,450] => 451-entry LUT
//  mean dist via cell histogram: sum = SUM_{c1,c2} h[c1] h[c2] sqrt(d2)

#define NQ    900
#define LUT_N 451

// ws layout (ints): centp[450] — packed u8x4 centers, word j of batch b at
// centp[b*225 + j] covering queries 4j..4j+3. Block blk of k1 produces
// exactly word blk (queries 4blk..4blk+3; 225 words per batch align).
__global__ __launch_bounds__(256)
void k1_centers(const float* __restrict__ ref, int* __restrict__ ws) {
    __shared__ int ctmp[4];
    const int tid  = threadIdx.x;
    const int lane = tid & 63;
    const int wave = tid >> 6;
    const int q    = blockIdx.x * 4 + wave;            // 0..1799

    // one float4 per lane covers the full 256-float map, coalesced 1KB/wave
    const float4* p4 = (const float4*)(ref + (size_t)q * 256);
    float4 v = p4[lane];
    float bv = v.x; int bi = lane * 4;
    if (v.y > bv) { bv = v.y; bi = lane * 4 + 1; }     // strict > = first max
    if (v.z > bv) { bv = v.z; bi = lane * 4 + 2; }
    if (v.w > bv) { bv = v.w; bi = lane * 4 + 3; }
    #pragma unroll
    for (int off = 32; off >= 1; off >>= 1) {
        float ov = __shfl_down(bv, off, 64);
        int   oi = __shfl_down(bi, off, 64);
        if (ov > bv || (ov == bv && oi < bi)) { bv = ov; bi = oi; }
    }
    if (lane == 0) ctmp[wave] = bi;                    // iy*16+ix, fits u8
    __syncthreads();
    if (tid == 0)
        ws[blockIdx.x] = (ctmp[0] & 255)        | ((ctmp[1] & 255) << 8) |
                         ((ctmp[2] & 255) << 16) | ((ctmp[3] & 255) << 24);
}

// k2: grid (99,2), 256 thr. 8 float4/thread (linear addresses: issue loads
// first, they drain at the first barrier while LDS setup runs). Then
// redundant per-block stats, then apply+store. 198 blocks <= 256 CUs so the
// redundant stats never serialize two-deep on a CU.
__global__ __launch_bounds__(256)
void k2_stats_apply(const float* __restrict__ attn,
                    const float* __restrict__ lam_p,
                    const float* __restrict__ w1,
                    const float* __restrict__ b1,
                    const float* __restrict__ w2,
                    const float* __restrict__ b2,
                    const int* __restrict__ ws,
                    float* __restrict__ out) {
    const int tid  = threadIdx.x;
    const int lane = tid & 63;
    const int wave = tid >> 6;
    const int b    = blockIdx.y;

    // ---- phase A: issue attn loads (addresses are pure linear in f4) ----
    const float4* attn4 = (const float4*)attn;
    float4*       out4  = (float4*)out;
    const int f4l = blockIdx.x * 2048 + tid;           // batch-local float4 idx
    float4 a[8];
    if (blockIdx.x < 98) {
        #pragma unroll
        for (int u = 0; u < 8; ++u)
            a[u] = attn4[(size_t)b * 202500 + f4l + u * 256];
    } else {
        #pragma unroll
        for (int u = 0; u < 8; ++u)
            if (f4l + u * 256 < 202500)
                a[u] = attn4[(size_t)b * 202500 + f4l + u * 256];
    }

    // ---- phase B: LDS setup (overlaps load latency) ----
    __shared__ int   cpk[225];                         // packed centers
    __shared__ int   hsh[256];
    __shared__ float sqs[LUT_N];
    __shared__ float w1s[256], b1s[256], wbars[256];
    __shared__ float lut_s[LUT_N];
    __shared__ float wsum[4];

    if (tid < 225) cpk[tid] = ws[b * 225 + tid];
    hsh[tid] = 0;
    w1s[tid] = w1[tid];
    b1s[tid] = b1[tid];
    {
        float s8 = 0.f;
        #pragma unroll
        for (int h = 0; h < 8; ++h) s8 += w2[tid * 8 + h];
        wbars[tid] = s8 * 0.125f;
    }
    for (int s = tid; s < LUT_N; s += 256) sqs[s] = sqrtf((float)s);
    __syncthreads();

    // ---- histogram of cells ----
    for (int k = tid; k < NQ; k += 256) {
        int c = (cpk[k >> 2] >> ((k & 3) * 8)) & 255;
        atomicAdd(&hsh[c], 1);
    }
    __syncthreads();

    // ---- pairwise mean via cell histogram (verbatim from R9) ----
    float local = 0.f;
    {
        int h2v = hsh[tid];                            // thread owns c2 = tid
        if (h2v) {
            int ix2 = tid & 15, iy2 = tid >> 4;
            for (int c1 = 0; c1 < 256; ++c1) {
                int h1 = hsh[c1];                      // broadcast read
                int dx = (c1 & 15) - ix2;
                int dy = (c1 >> 4) - iy2;
                local += (float)h1 * sqs[dx * dx + dy * dy];
            }
            local *= (float)h2v;
        }
    }
    #pragma unroll
    for (int off = 32; off >= 1; off >>= 1) local += __shfl_down(local, off, 64);
    if (lane == 0) wsum[wave] = local;
    __syncthreads();

    float tot   = wsum[0] + wsum[1] + wsum[2] + wsum[3];
    float mean  = tot * (1.f / 15.f) * (1.f / ((float)NQ * (float)NQ));
    float inv   = 1.f / (mean + 1e-6f);
    float b2bar = 0.125f * (b2[0] + b2[1] + b2[2] + b2[3] +
                            b2[4] + b2[5] + b2[6] + b2[7]);
    float lam   = lam_p[0];

    // ---- LUT: entries tid and tid+256, interleaved loop (each accumulator
    //      chain is the identical per-entry fmaf sequence from R9) ----
    {
        float t0   = sqs[tid] * (1.f / 15.f) * inv;
        bool  has1 = (tid + 256 < LUT_N);              // tid < 195
        float t1   = has1 ? sqs[tid + 256] * (1.f / 15.f) * inv : 0.f;
        float acc0 = b2bar, acc1 = b2bar;
        for (int i = 0; i < 256; ++i) {
            float w  = w1s[i];
            float bb = b1s[i];
            float wb = wbars[i];
            float h0 = fmaf(t0, w, bb);
            acc0 = fmaf(fmaxf(h0, 0.f), wb, acc0);
            float h1 = fmaf(t1, w, bb);
            acc1 = fmaf(fmaxf(h1, 0.f), wb, acc1);
        }
        lut_s[tid] = lam * acc0;
        if (has1) lut_s[tid + 256] = lam * acc1;
    }
    __syncthreads();

    // ---- phase D: apply + store ----
    #pragma unroll
    for (int u = 0; u < 8; ++u) {
        int f4 = f4l + u * 256;
        if (f4 < 202500) {
            int i  = (int)((unsigned)f4 / 225u);       // row 0..899
            int j4 = f4 - i * 225;                     // float4 within row
            int ci = (cpk[i >> 2] >> ((i & 3) * 8)) & 255;   // mostly broadcast
            int ixi = ci & 15, iyi = ci >> 4;
            int cw = cpk[j4];                          // stride-1, conflict-free
            float4 v = a[u];
            int c, dx, dy;
            c = cw & 255;         dx = ixi - (c & 15); dy = iyi - (c >> 4); v.x += lut_s[dx*dx + dy*dy];
            c = (cw >> 8) & 255;  dx = ixi - (c & 15); dy = iyi - (c >> 4); v.y += lut_s[dx*dx + dy*dy];
            c = (cw >> 16) & 255; dx = ixi - (c & 15); dy = iyi - (c >> 4); v.z += lut_s[dx*dx + dy*dy];
            c = (cw >> 24) & 255; dx = ixi - (c & 15); dy = iyi - (c >> 4); v.w += lut_s[dx*dx + dy*dy];
            out4[(size_t)b * 202500 + f4] = v;
        }
    }
}

extern "C" void kernel_launch(void* const* d_in, const int* in_sizes, int n_in,
                              void* d_out, int out_size, void* d_ws, size_t ws_size,
                              hipStream_t stream) {
    const float* attn = (const float*)d_in[0];   // [2,900,900]
    const float* ref  = (const float*)d_in[1];   // [2,900,16,16]
    const float* lam  = (const float*)d_in[2];
    const float* w1   = (const float*)d_in[3];   // [256]
    const float* b1   = (const float*)d_in[4];   // [256]
    const float* w2   = (const float*)d_in[5];   // [256,8]
    const float* b2   = (const float*)d_in[6];   // [8]
    float* out = (float*)d_out;
    int*   ws  = (int*)d_ws;                     // centp[450]

    k1_centers<<<450, 256, 0, stream>>>(ref, ws);
    k2_stats_apply<<<dim3(99, 2), 256, 0, stream>>>(attn, lam, w1, b1, w2, b2, ws, out);
}